// Round 1
// baseline (10.973 us; speedup 1.0000x reference)
//
#include <hip/hip_runtime.h>

// Problem constants (from reference):
//   R=4, B=2048, S=10, U=20000, D=128
// Output: [R*B, D] fp32 = mean over the SET (dedup'd) of sampled neighbor embeddings.

#define RR 4
#define BB 2048
#define SS 10
#define UU 20000
#define DD 128

// One thread computes one float4 (4 of the 128 output features) of one row.
// 32 threads per row; a 64-lane wave covers 2 rows.
__global__ __launch_bounds__(256) void mean_agg_kernel(
    const int* __restrict__ neigh_idx,   // [R*B, S]
    const float* __restrict__ embed,     // [U, D]
    float* __restrict__ out)             // [R*B, D]
{
    const int t   = blockIdx.x * blockDim.x + threadIdx.x;
    const int row = t >> 5;          // 32 threads per row
    const int c4  = t & 31;          // which float4 within the row
    if (row >= RR * BB) return;

    // Load the row's S indices (all 32 lanes of the row read the same 40 B —
    // L1 broadcast, negligible).
    int id[SS];
    const int* ip = neigh_idx + row * SS;
    #pragma unroll
    for (int j = 0; j < SS; ++j) id[j] = ip[j];

    float4 acc = make_float4(0.f, 0.f, 0.f, 0.f);
    int cnt = 0;
    #pragma unroll
    for (int j = 0; j < SS; ++j) {
        // keep j only if no earlier duplicate (set semantics)
        bool dup = false;
        #pragma unroll
        for (int i = 0; i < j; ++i) dup = dup || (id[i] == id[j]);
        if (!dup) {
            ++cnt;
            const float4 v = *reinterpret_cast<const float4*>(
                embed + (size_t)id[j] * DD + (c4 << 2));
            acc.x += v.x; acc.y += v.y; acc.z += v.z; acc.w += v.w;
        }
    }
    // S>=1 so cnt>=1 always; reference's zero-guard can't trigger.
    const float inv = 1.0f / (float)cnt;
    acc.x *= inv; acc.y *= inv; acc.z *= inv; acc.w *= inv;

    reinterpret_cast<float4*>(out)[row * 32 + c4] = acc;
}

extern "C" void kernel_launch(void* const* d_in, const int* in_sizes, int n_in,
                              void* d_out, int out_size, void* d_ws, size_t ws_size,
                              hipStream_t stream) {
    const int*   neigh_idx = (const int*)d_in[0];    // [R,B,S] int32
    const float* embed     = (const float*)d_in[1];  // [U,D] fp32
    float*       out       = (float*)d_out;          // [R*B, D] fp32

    const int rows    = RR * BB;           // 8192
    const int threads = rows * 32;         // one thread per float4 of output
    const int block   = 256;
    const int grid    = (threads + block - 1) / block;  // 1024

    mean_agg_kernel<<<grid, block, 0, stream>>>(neigh_idx, embed, out);
}

// Round 2
// 9.871 us; speedup vs baseline: 1.1116x; 1.1116x over previous
//
#include <hip/hip_runtime.h>

// Problem constants (from reference):
//   R=4, B=2048, S=10, U=20000, D=128
// Output: [R*B, D] fp32 = mean over the SET (dedup'd) of sampled neighbor embeddings.

#define RR 4
#define BB 2048
#define SS 10
#define UU 20000
#define DD 128
#define ROWS (RR * BB)          // 8192
#define NCHUNK 8                // column chunks of 16 floats, pinned to XCDs

typedef float vfloat4 __attribute__((ext_vector_type(4)));

// Grid decomposition: blockIdx & 7 = column chunk (16 floats) -> lands on one
// XCD via round-robin dispatch, so each XCD's L2 only holds a 20000 x 64 B
// = 1.28 MB slice of the embed table (fully L2-resident gathers).
// Block: 256 threads = 64 rows x 4 float4-lanes.
__global__ __launch_bounds__(256) void mean_agg_kernel(
    const int* __restrict__ neigh_idx,   // [ROWS, S]
    const float* __restrict__ embed,     // [U, D]
    float* __restrict__ out)             // [ROWS, D]
{
    const int chunk  = blockIdx.x & (NCHUNK - 1);
    const int group  = blockIdx.x >> 3;           // row group of 64
    const int tid    = threadIdx.x;
    const int rlocal = tid >> 2;                  // 0..63
    const int c4l    = tid & 3;                   // 0..3
    const int row    = group * 64 + rlocal;
    const int col4   = chunk * 4 + c4l;           // float4 index within row, 0..31

    // Row's S indices: 4 lanes per row read the same 40 B (L1 broadcast).
    int id[SS];
    const int* ip = neigh_idx + row * SS;
    #pragma unroll
    for (int j = 0; j < SS; ++j) id[j] = ip[j];

    const vfloat4* __restrict__ esrc =
        reinterpret_cast<const vfloat4*>(embed) + col4;

    vfloat4 acc = (vfloat4){0.f, 0.f, 0.f, 0.f};
    int cnt = 0;
    #pragma unroll
    for (int j = 0; j < SS; ++j) {
        // set semantics: keep j only if no earlier duplicate
        bool dup = false;
        #pragma unroll
        for (int i = 0; i < j; ++i) dup = dup || (id[i] == id[j]);
        if (!dup) {
            ++cnt;
            acc += esrc[(size_t)id[j] * (DD / 4)];
        }
    }
    // S>=1 so cnt>=1 always; reference's zero-guard can't trigger.
    acc *= (1.0f / (float)cnt);

    // Nontemporal: don't let the 4 MB output evict the embed slice from L2.
    __builtin_nontemporal_store(
        acc, reinterpret_cast<vfloat4*>(out) + (size_t)row * 32 + col4);
}

extern "C" void kernel_launch(void* const* d_in, const int* in_sizes, int n_in,
                              void* d_out, int out_size, void* d_ws, size_t ws_size,
                              hipStream_t stream) {
    const int*   neigh_idx = (const int*)d_in[0];    // [R,B,S] int32
    const float* embed     = (const float*)d_in[1];  // [U,D] fp32
    float*       out       = (float*)d_out;          // [ROWS, D] fp32

    const int block = 256;
    const int grid  = (ROWS / 64) * NCHUNK;          // 128 * 8 = 1024 blocks

    mean_agg_kernel<<<grid, block, 0, stream>>>(neigh_idx, embed, out);
}